// Round 3
// baseline (1772.554 us; speedup 1.0000x reference)
//
#include <hip/hip_runtime.h>
#include <hip/hip_cooperative_groups.h>
#include <stdint.h>

namespace cg = cooperative_groups;

typedef unsigned long long ull;
typedef unsigned short ushort_t;
typedef __attribute__((ext_vector_type(8))) short bf16x8;
typedef __attribute__((ext_vector_type(4))) float f32x4;

// sizes: b=64, f=4, v=256, d=16384, ITERS=10; d-words = 256, v-words = 4
//
// ws layout (bytes):
//   in_bits [64][256] ull        @ 0         (131072)
//   est     [64][4][256] ull     @ 131072    (524288)   (in-place across iterations)
//   cbw     [4][256][256] ull    @ 1179648   (2097152)  [f][w][v]: bit l = sign cb[f][v][w*64+l]
//   cbT     [4][4][16384] ull    @ 3276800   (2097152)  [f][j][d]: bit l = sign cb[f][j*64+l][d]
//   simAB   [4][64][512] ushort  @ 5373952   (262144)   [..][0:256]=uh bf16, [256:512]=ul bf16
//   offc    [4][16384] int       @ 5636096   (262144)   8192*colsum[f][d]
//
// bit convention: bit = 1  <=>  value == -1;  product of bipolars = XOR of bits.

__global__ void pack_bits(const float* __restrict__ src, ull* __restrict__ dst, int nwords) {
    int gw   = (int)((blockIdx.x * blockDim.x + threadIdx.x) >> 6);
    int lane = threadIdx.x & 63;
    if (gw >= nwords) return;
    float x = src[(size_t)gw * 64 + lane];
    ull m = __ballot(x < 0.0f);
    if (lane == 0) dst[gw] = m;
}

__global__ void pack_cbw(const float* __restrict__ cb, ull* __restrict__ cbw) {
    int gw   = (int)((blockIdx.x * blockDim.x + threadIdx.x) >> 6);
    int lane = threadIdx.x & 63;
    int f = gw >> 16, rem = gw & 65535, w = rem >> 8, v = rem & 255;
    float x = cb[(size_t)(f * 256 + v) * 16384 + (size_t)w * 64 + lane];
    ull m = __ballot(x < 0.0f);
    if (lane == 0) cbw[(size_t)(f * 256 + w) * 256 + v] = m;
}

__global__ void pack_cbT(const ull* __restrict__ cbw, ull* __restrict__ cbT) {
    int gw   = (int)((blockIdx.x * blockDim.x + threadIdx.x) >> 6);
    int lane = threadIdx.x & 63;
    int f = gw >> 16, rem = gw & 65535, j = rem >> 14, d = rem & 16383;
    ull w = cbw[(size_t)(f * 256 + (d >> 6)) * 256 + j * 64 + lane];
    ull m = __ballot((w >> (d & 63)) & 1ull);
    if (lane == 0) cbT[(size_t)(f * 4 + j) * 16384 + d] = m;
}

__global__ void make_offc(const ull* __restrict__ cbT, int* __restrict__ offc) {
    int i = blockIdx.x * 256 + threadIdx.x;   // 4*16384
    int f = i >> 14, d = i & 16383;
    int npop = 0;
    #pragma unroll
    for (int j = 0; j < 4; ++j) npop += __popcll(cbT[((size_t)f * 4 + j) * 16384 + d]);
    offc[i] = 8192 * (256 - 2 * npop);        // 8192 * colsum
}

__device__ __forceinline__ ushort_t f2bf(int x) {
    // exact for 0 <= x <= 256 (<= 8 significant bits)
    return (ushort_t)(__float_as_uint((float)x) >> 16);
}

// ONE cooperative kernel: 10 x (phase A popcount-sim -> sync -> phase B MFMA-update -> sync) + final.
// grid = 256 blocks x 512 threads, 1 block/CU (149.5KB LDS).
// A-role: (bA, fA) = blockIdx; B-role: (fB, dblk) = blockIdx.
__global__ __launch_bounds__(512) void fused_kernel(
        const ull* __restrict__ in_bits, ull* __restrict__ est,
        const ull* __restrict__ cbw, const ull* __restrict__ cbT,
        const int* __restrict__ offc, ushort_t* __restrict__ simAB,
        float* __restrict__ out) {
    cg::grid_group grid = cg::this_grid();
    int t = threadIdx.x;
    int lane = t & 63, wave = t >> 6;
    int bA = blockIdx.x >> 2, fA = blockIdx.x & 3;
    int fB = blockIdx.x >> 6, dblk = blockIdx.x & 63;

    __shared__ int4 sB[8192];                  // 128KB  B-frags, staged ONCE
    __shared__ unsigned char s_sign[64][256];  // 16KB
    __shared__ ull s_ne[256];                  // 2KB
    __shared__ short s_hp[2][256];             // 1KB
    __shared__ int s_off[256];                 // 1KB
    __shared__ int s_sim[256];                 // 1KB

    // ---- one-time B-role staging: unpack codebook bits -> bf16 MFMA B-frags ----
    if (t < 256) s_off[t] = offc[fB * 16384 + dblk * 256 + t];
    #pragma unroll 4
    for (int it = 0; it < 16; ++it) {
        int flat = it * 512 + t;               // 8 kc * 16 nt * 64 lanes
        int kc = flat >> 10, nt = (flat >> 6) & 15, l = flat & 63;
        int v0 = kc * 32 + ((l >> 4) << 3);
        int d  = dblk * 256 + nt * 16 + (l & 15);
        ull w = cbT[((size_t)fB * 4 + (v0 >> 6)) * 16384 + d];
        unsigned bits = (unsigned)(w >> (v0 & 63)) & 0xFFu;
        int4 val;
        val.x = 0x3F803F80 | ((bits & 1u) << 15)        | ((bits & 2u) << 30);
        val.y = 0x3F803F80 | (((bits >> 2) & 1u) << 15) | (((bits >> 2) & 2u) << 30);
        val.z = 0x3F803F80 | (((bits >> 4) & 1u) << 15) | (((bits >> 4) & 2u) << 30);
        val.w = 0x3F803F80 | (((bits >> 6) & 1u) << 15) | (((bits >> 6) & 2u) << 30);
        sB[flat] = val;
    }
    // first __syncthreads below (phase A) publishes sB/s_off block-wide.

    const int mw = wave & 3;                   // B-role m-tile (16 b rows)
    const int ntb = (wave >> 2) << 3;          // B-role nt half: 0..7 or 8..15
    const ushort_t* abase = simAB
        + ((size_t)(fB * 64 + mw * 16 + (lane & 15))) * 512 + ((lane >> 4) << 3);

    for (int itr = 0; itr < 10; ++itr) {
        // ================= phase A: q[v] via popcount =================
        if (t < 256) {
            ull e0 = est[(size_t)(bA * 4 + 0) * 256 + t];
            ull e1 = est[(size_t)(bA * 4 + 1) * 256 + t];
            ull e2 = est[(size_t)(bA * 4 + 2) * 256 + t];
            ull e3 = est[(size_t)(bA * 4 + 3) * 256 + t];
            ull u  = in_bits[(size_t)bA * 256 + t] ^ e0 ^ e1 ^ e2 ^ e3;
            ull ef = (fA == 0) ? e0 : ((fA == 1) ? e1 : ((fA == 2) ? e2 : e3));
            s_ne[t] = u ^ ef;
        }
        __syncthreads();
        {
            int v = t & 255, half = t >> 8;
            const ull* cw = cbw + (size_t)fA * 65536 + (size_t)(half * 128) * 256 + v;
            int acc = 0;
            #pragma unroll 16
            for (int w = 0; w < 128; ++w)
                acc += __popcll(s_ne[half * 128 + w] ^ cw[(size_t)w * 256]);
            s_hp[half][v] = (short)acc;
        }
        __syncthreads();
        if (t < 256) {
            int q = 16384 - (s_hp[0][t] + s_hp[1][t]);     // in [0,16384]
            size_t base = ((size_t)(fA * 64 + bA)) * 512 + t;
            simAB[base]       = f2bf(q >> 8);              // uh in [0,64]
            simAB[base + 256] = f2bf(q & 255);             // ul in [0,255]
        }
        __threadfence();
        grid.sync();

        // ================= phase B: est = sign(GEMM) via MFMA =================
        bf16x8 Ahi[8], Alo[8];
        #pragma unroll
        for (int kc = 0; kc < 8; ++kc) {
            Ahi[kc] = *(const bf16x8*)(abase + kc * 32);
            Alo[kc] = *(const bf16x8*)(abase + 256 + kc * 32);
        }
        #pragma unroll 1
        for (int nt = ntb; nt < ntb + 8; ++nt) {
            f32x4 acch = {0.f, 0.f, 0.f, 0.f}, accl = {0.f, 0.f, 0.f, 0.f};
            #pragma unroll
            for (int kc = 0; kc < 8; ++kc) {
                bf16x8 B = *(const bf16x8*)&sB[(kc * 16 + nt) * 64 + lane];
                acch = __builtin_amdgcn_mfma_f32_16x16x32_bf16(Ahi[kc], B, acch, 0, 0, 0);
                accl = __builtin_amdgcn_mfma_f32_16x16x32_bf16(Alo[kc], B, accl, 0, 0, 0);
            }
            int dl = nt * 16 + (lane & 15);
            float offf = (float)s_off[dl];
            #pragma unroll
            for (int r = 0; r < 4; ++r) {
                float S = 256.0f * acch[r] + accl[r];      // exact int < 2^23
                s_sign[mw * 16 + ((lane >> 4) << 2) + r][dl] = (S < offf) ? 1 : 0;
            }
        }
        __syncthreads();
        if (t < 256) {
            int b = t >> 2, w4 = t & 3;
            ull m = 0;
            #pragma unroll
            for (int j2 = 0; j2 < 64; ++j2)
                m |= ((ull)s_sign[b][w4 * 64 + j2]) << j2;
            est[((size_t)(b * 4 + fB)) * 256 + dblk * 4 + w4] = m;
        }
        __threadfence();
        grid.sync();
    }

    // ================= final: sim(est), argmax|sim|, unpack est =================
    if (t < 256) s_ne[t] = est[(size_t)(bA * 4 + fA) * 256 + t];
    __syncthreads();
    {
        int v = t & 255, half = t >> 8;
        const ull* cw = cbw + (size_t)fA * 65536 + (size_t)(half * 128) * 256 + v;
        int acc = 0;
        #pragma unroll 16
        for (int w = 0; w < 128; ++w)
            acc += __popcll(s_ne[half * 128 + w] ^ cw[(size_t)w * 256]);
        s_hp[half][v] = (short)acc;
    }
    __syncthreads();
    if (t < 256) s_sim[t] = 16384 - 2 * (s_hp[0][t] + s_hp[1][t]);
    __syncthreads();
    if (wave == 0) {
        int best_a = -1, best_v = 0;
        #pragma unroll
        for (int c = 0; c < 4; ++c) {
            int v = c * 64 + lane;
            int sv = s_sim[v];
            int a = sv < 0 ? -sv : sv;
            if (a > best_a) { best_a = a; best_v = v; }   // strict > keeps first index
        }
        #pragma unroll
        for (int off = 1; off < 64; off <<= 1) {
            int oa = __shfl_xor(best_a, off);
            int ov = __shfl_xor(best_v, off);
            if (oa > best_a || (oa == best_a && ov < best_v)) { best_a = oa; best_v = ov; }
        }
        if (lane == 0) out[4194304 + bA * 4 + fA] = (float)best_v;
    }
    #pragma unroll
    for (int i = 0; i < 32; ++i) {
        int d = i * 512 + t;
        ull w = s_ne[d >> 6];
        out[((size_t)(bA * 4 + fA) << 14) + d] = ((w >> (d & 63)) & 1ull) ? -1.0f : 1.0f;
    }
}

extern "C" void kernel_launch(void* const* d_in, const int* in_sizes, int n_in,
                              void* d_out, int out_size, void* d_ws, size_t ws_size,
                              hipStream_t stream) {
    const float* input    = (const float*)d_in[0];
    const float* init_est = (const float*)d_in[1];
    const float* cb       = (const float*)d_in[2];
    float* out = (float*)d_out;
    char* ws = (char*)d_ws;

    const ull* in_bits = (const ull*)(ws + 0);
    ull* est           = (ull*)(ws + 131072);
    const ull* cbw     = (const ull*)(ws + 1179648);
    ull* cbT           = (ull*)(ws + 3276800);
    ushort_t* simAB    = (ushort_t*)(ws + 5373952);
    int* offc          = (int*)(ws + 5636096);

    pack_bits<<<4096, 256, 0, stream>>>(input, (ull*)in_bits, 16384);
    pack_bits<<<16384, 256, 0, stream>>>(init_est, est, 65536);
    pack_cbw<<<65536, 256, 0, stream>>>(cb, (ull*)cbw);
    pack_cbT<<<65536, 256, 0, stream>>>(cbw, cbT);
    make_offc<<<256, 256, 0, stream>>>(cbT, offc);

    void* kargs[] = {
        (void*)&in_bits, (void*)&est, (void*)&cbw, (void*)&cbT,
        (void*)&offc, (void*)&simAB, (void*)&out
    };
    hipLaunchCooperativeKernel(reinterpret_cast<void*>(fused_kernel),
                               dim3(256, 1, 1), dim3(512, 1, 1), kargs, 0, stream);
}

// Round 4
// 378.165 us; speedup vs baseline: 4.6873x; 4.6873x over previous
//
#include <hip/hip_runtime.h>
#include <stdint.h>

typedef unsigned long long ull;
typedef unsigned short ushort_t;
typedef __attribute__((ext_vector_type(8))) short bf16x8;
typedef __attribute__((ext_vector_type(4))) float f32x4;

// sizes: b=64, f=4, v=256, d=16384, ITERS=10; d-words = 256, v-words = 4
//
// ws layout (bytes):
//   in_bits [64][256] ull        @ 0         (131072)
//   est0    [64][4][256] ull     @ 131072    (524288)
//   est1    [64][4][256] ull     @ 655360    (524288)
//   cbw     [4][256][256] ull    @ 1179648   (2097152)  [f][w][v]: bit l = sign cb[f][v][w*64+l]
//   cbT     [4][4][16384] ull    @ 3276800   (2097152)  [f][j][d]: bit l = sign cb[f][j*64+l][d]
//   simAB   [4][64][512] ushort  @ 5373952   (262144)   [..][0:256]=uh bf16, [256:512]=ul bf16
//
// bit convention: bit = 1  <=>  value == -1;  product of bipolars = XOR of bits.

// ---- setup: pack input + init_estimates in ONE dispatch ----
__global__ __launch_bounds__(1024) void pack_all(
        const float* __restrict__ in, const float* __restrict__ est_f,
        ull* __restrict__ in_bits, ull* __restrict__ est_bits) {
    int gw   = (int)((blockIdx.x * 1024 + threadIdx.x) >> 6);   // 81920 waves
    int lane = threadIdx.x & 63;
    if (gw < 16384) {
        float x = in[(size_t)gw * 64 + lane];
        ull m = __ballot(x < 0.0f);
        if (lane == 0) in_bits[gw] = m;
    } else {
        int g = gw - 16384;
        float x = est_f[(size_t)g * 64 + lane];
        ull m = __ballot(x < 0.0f);
        if (lane == 0) est_bits[g] = m;
    }
}

// wave order (f,v,w): block reads 4KB contiguous from cb (HBM coalescing)
__global__ __launch_bounds__(1024) void pack_cbw(const float* __restrict__ cb, ull* __restrict__ cbw) {
    int gw   = (int)((blockIdx.x * 1024 + threadIdx.x) >> 6);   // (f*256+v)*256 + w
    int lane = threadIdx.x & 63;
    int w = gw & 255, fv = gw >> 8;
    float x = cb[(size_t)fv * 16384 + (size_t)w * 64 + lane];
    ull m = __ballot(x < 0.0f);
    if (lane == 0) cbw[(size_t)((fv >> 8) * 256 + w) * 256 + (fv & 255)] = m;
}

__global__ __launch_bounds__(1024) void pack_cbT(const ull* __restrict__ cbw, ull* __restrict__ cbT) {
    int gw   = (int)((blockIdx.x * 1024 + threadIdx.x) >> 6);
    int lane = threadIdx.x & 63;
    int f = gw >> 16, rem = gw & 65535, j = rem >> 14, d = rem & 16383;
    ull w = cbw[(size_t)(f * 256 + (d >> 6)) * 256 + j * 64 + lane];
    ull m = __ballot((w >> (d & 63)) & 1ull);
    if (lane == 0) cbT[(size_t)(f * 4 + j) * 16384 + d] = m;
}

__device__ __forceinline__ ushort_t f2bf(int x) {
    // exact for 0 <= x <= 256 (<= 8 significant bits)
    return (ushort_t)(__float_as_uint((float)x) >> 16);
}

// phase A: one block per (b,f), 1024 threads (4-way w-split shortens load chain)
__global__ __launch_bounds__(1024) void simA_kernel(
        const ull* __restrict__ in_bits, const ull* __restrict__ est_in,
        const ull* __restrict__ cbw, ushort_t* __restrict__ simAB) {
    int bA = blockIdx.x >> 2, fA = blockIdx.x & 3;
    __shared__ ull s_ne[256];
    __shared__ short s_hp[4][256];
    int t = threadIdx.x;
    if (t < 256) {
        ull e0 = est_in[(size_t)(bA * 4 + 0) * 256 + t];
        ull e1 = est_in[(size_t)(bA * 4 + 1) * 256 + t];
        ull e2 = est_in[(size_t)(bA * 4 + 2) * 256 + t];
        ull e3 = est_in[(size_t)(bA * 4 + 3) * 256 + t];
        ull u  = in_bits[(size_t)bA * 256 + t] ^ e0 ^ e1 ^ e2 ^ e3;
        ull ef = (fA == 0) ? e0 : ((fA == 1) ? e1 : ((fA == 2) ? e2 : e3));
        s_ne[t] = u ^ ef;
    }
    __syncthreads();
    {
        int v = t & 255, qr = t >> 8;                 // quarter 0..3 = 64 w each
        const ull* cw = cbw + (size_t)fA * 65536 + (size_t)(qr * 64) * 256 + v;
        int acc = 0;
        #pragma unroll 16
        for (int w = 0; w < 64; ++w)
            acc += __popcll(s_ne[qr * 64 + w] ^ cw[(size_t)w * 256]);
        s_hp[qr][v] = (short)acc;
    }
    __syncthreads();
    if (t < 256) {
        int q = 16384 - (s_hp[0][t] + s_hp[1][t] + s_hp[2][t] + s_hp[3][t]);  // [0,16384]
        size_t base = ((size_t)(fA * 64 + bA)) * 512 + t;
        simAB[base]       = f2bf(q >> 8);             // uh in [0,64]
        simAB[base + 256] = f2bf(q & 255);            // ul in [0,255]
    }
}

// phase B: one block per (f, dblk of 256 d), 512 threads (8 waves: 4 m-tiles x 2 nt-halves)
// est_bit(b,d) = ( 256*sum_v uh*cb + sum_v ul*cb < 8192*colsum )
// epilogue: __ballot -> 2KB s_ball (no byte-transpose LDS, no bank conflicts)
__global__ __launch_bounds__(512) void gemm_kernel(
        const ull* __restrict__ cbT, const ushort_t* __restrict__ simAB,
        ull* __restrict__ est_out) {
    int fB = blockIdx.x >> 6, dblk = blockIdx.x & 63;
    __shared__ int4 sB[8192];               // 128KB, frag order: (kc*16+nt)*64 + lane
    __shared__ ull s_ball[8][8][4];         // 2KB  [wave][nt&7][r]
    __shared__ int s_off[256];              // 1KB
    int t = threadIdx.x, lane = t & 63, wave = t >> 6;

    // s_off from cbT directly (folds old make_offc kernel)
    if (t < 256) {
        int d = dblk * 256 + t;
        int npop = 0;
        #pragma unroll
        for (int j = 0; j < 4; ++j) npop += __popcll(cbT[((size_t)fB * 4 + j) * 16384 + d]);
        s_off[t] = 8192 * (256 - 2 * npop);
    }

    // unpack codebook bits -> bf16 MFMA B-frags in LDS (16 int4 per thread)
    #pragma unroll 4
    for (int it = 0; it < 16; ++it) {
        int flat = it * 512 + t;            // 8 kc * 16 nt * 64 lanes
        int kc = flat >> 10, nt = (flat >> 6) & 15, l = flat & 63;
        int v0 = kc * 32 + ((l >> 4) << 3);
        int d  = dblk * 256 + nt * 16 + (l & 15);
        ull w = cbT[((size_t)fB * 4 + (v0 >> 6)) * 16384 + d];
        unsigned bits = (unsigned)(w >> (v0 & 63)) & 0xFFu;
        int4 val;
        val.x = 0x3F803F80 | ((bits & 1u) << 15)        | ((bits & 2u) << 30);
        val.y = 0x3F803F80 | (((bits >> 2) & 1u) << 15) | (((bits >> 2) & 2u) << 30);
        val.z = 0x3F803F80 | (((bits >> 4) & 1u) << 15) | (((bits >> 4) & 2u) << 30);
        val.w = 0x3F803F80 | (((bits >> 6) & 1u) << 15) | (((bits >> 6) & 2u) << 30);
        sB[flat] = val;
    }

    // A-frags from global simAB (L2-resident, written by preceding simA dispatch)
    int mw = wave & 3, ntb = (wave >> 2) << 3;
    const ushort_t* abase = simAB
        + ((size_t)(fB * 64 + mw * 16 + (lane & 15))) * 512 + ((lane >> 4) << 3);
    bf16x8 Ahi[8], Alo[8];
    #pragma unroll
    for (int kc = 0; kc < 8; ++kc) {
        Ahi[kc] = *(const bf16x8*)(abase + kc * 32);
        Alo[kc] = *(const bf16x8*)(abase + 256 + kc * 32);
    }
    __syncthreads();

    #pragma unroll 2
    for (int ntl = 0; ntl < 8; ++ntl) {
        int nt = ntb + ntl;
        f32x4 acch = {0.f, 0.f, 0.f, 0.f}, accl = {0.f, 0.f, 0.f, 0.f};
        #pragma unroll
        for (int kc = 0; kc < 8; ++kc) {
            bf16x8 B = *(const bf16x8*)&sB[(kc * 16 + nt) * 64 + lane];
            acch = __builtin_amdgcn_mfma_f32_16x16x32_bf16(Ahi[kc], B, acch, 0, 0, 0);
            accl = __builtin_amdgcn_mfma_f32_16x16x32_bf16(Alo[kc], B, accl, 0, 0, 0);
        }
        float offf = (float)s_off[nt * 16 + (lane & 15)];
        #pragma unroll
        for (int r = 0; r < 4; ++r) {
            float S = 256.0f * acch[r] + accl[r];   // exact int < 2^23
            // C-frag: row m = mw*16 + (lane>>4)*4 + r, col d-local = lane&15
            // ballot bit (g*16+dl) = est bit for (m = mw*16+g*4+r, d = dblk*256+nt*16+dl)
            ull m = __ballot(S < offf);
            if (lane == 0) s_ball[wave][nt & 7][r] = m;
        }
    }
    __syncthreads();

    if (t < 256) {
        int b = t >> 2, w4 = t & 3;                 // est word (b, d-word dblk*4+w4)
        int wv = (b >> 4) + ((w4 >= 2) ? 4 : 0);    // writer wave for (mw=b>>4, nt-half)
        ull word = 0;
        #pragma unroll
        for (int k = 0; k < 4; ++k) {
            int nt = w4 * 4 + k;
            ull m = s_ball[wv][nt & 7][b & 3];
            word |= ((m >> (((b >> 2) & 3) * 16)) & 0xFFFFull) << (k * 16);
        }
        est_out[((size_t)(b * 4 + fB)) * 256 + dblk * 4 + w4] = word;
    }
}

// final: sim from est bits, argmax|sim| (first-index ties), unpack est to floats
__global__ __launch_bounds__(1024) void final_kernel(
        const ull* __restrict__ est, const ull* __restrict__ cbw, float* __restrict__ out) {
    int b = blockIdx.x >> 2, f = blockIdx.x & 3;
    __shared__ ull s_e[256];
    __shared__ short s_hp[4][256];
    __shared__ int s_sim[256];
    int t = threadIdx.x;
    if (t < 256) s_e[t] = est[(size_t)(b * 4 + f) * 256 + t];
    __syncthreads();
    {
        int v = t & 255, qr = t >> 8;
        const ull* cw = cbw + (size_t)f * 65536 + (size_t)(qr * 64) * 256 + v;
        int acc = 0;
        #pragma unroll 16
        for (int w = 0; w < 64; ++w)
            acc += __popcll(s_e[qr * 64 + w] ^ cw[(size_t)w * 256]);
        s_hp[qr][v] = (short)acc;
    }
    __syncthreads();
    if (t < 256) {
        int h = s_hp[0][t] + s_hp[1][t] + s_hp[2][t] + s_hp[3][t];
        s_sim[t] = 16384 - 2 * h;
    }
    __syncthreads();
    int wv = t >> 6, lane = t & 63;
    if (wv == 0) {
        int best_a = -1, best_v = 0;
        #pragma unroll
        for (int c = 0; c < 4; ++c) {
            int v = c * 64 + lane;
            int sv = s_sim[v];
            int a = sv < 0 ? -sv : sv;
            if (a > best_a) { best_a = a; best_v = v; }   // strict > keeps first index
        }
        #pragma unroll
        for (int off = 1; off < 64; off <<= 1) {
            int oa = __shfl_xor(best_a, off);
            int ov = __shfl_xor(best_v, off);
            if (oa > best_a || (oa == best_a && ov < best_v)) { best_a = oa; best_v = ov; }
        }
        if (lane == 0) out[4194304 + b * 4 + f] = (float)best_v;
    }
    #pragma unroll
    for (int i = 0; i < 16; ++i) {
        int d = i * 1024 + t;
        ull w = s_e[d >> 6];
        out[((size_t)(b * 4 + f) << 14) + d] = ((w >> (d & 63)) & 1ull) ? -1.0f : 1.0f;
    }
}

extern "C" void kernel_launch(void* const* d_in, const int* in_sizes, int n_in,
                              void* d_out, int out_size, void* d_ws, size_t ws_size,
                              hipStream_t stream) {
    const float* input    = (const float*)d_in[0];
    const float* init_est = (const float*)d_in[1];
    const float* cb       = (const float*)d_in[2];
    float* out = (float*)d_out;
    char* ws = (char*)d_ws;

    ull* in_bits    = (ull*)(ws + 0);
    ull* est0       = (ull*)(ws + 131072);
    ull* est1       = (ull*)(ws + 655360);
    ull* cbw        = (ull*)(ws + 1179648);
    ull* cbT        = (ull*)(ws + 3276800);
    ushort_t* simAB = (ushort_t*)(ws + 5373952);

    // setup: 3 dispatches
    pack_all<<<5120, 1024, 0, stream>>>(input, init_est, in_bits, est0);
    pack_cbw<<<16384, 1024, 0, stream>>>(cb, cbw);
    pack_cbT<<<16384, 1024, 0, stream>>>(cbw, cbT);

    ull* bufs[2] = { est0, est1 };
    for (int i = 0; i < 10; ++i) {
        simA_kernel<<<256, 1024, 0, stream>>>(in_bits, bufs[i & 1], cbw, simAB);
        gemm_kernel<<<256, 512, 0, stream>>>(cbT, simAB, bufs[(i & 1) ^ 1]);
    }
    // 10 iterations: final est is back in est0
    final_kernel<<<256, 1024, 0, stream>>>(est0, cbw, out);
}

// Round 6
// 363.422 us; speedup vs baseline: 4.8774x; 1.0406x over previous
//
#include <hip/hip_runtime.h>
#include <stdint.h>

typedef unsigned long long ull;
typedef unsigned short ushort_t;
typedef __attribute__((ext_vector_type(8))) short bf16x8;
typedef __attribute__((ext_vector_type(4))) float f32x4;

// sizes: b=64, f=4, v=256, d=16384, ITERS=10; d-words = 256, v-words = 4
//
// ws layout (bytes):
//   in_bits [64][256] ull        @ 0         (131072)
//   est0    [64][4][256] ull     @ 131072    (524288)
//   est1    [64][4][256] ull     @ 655360    (524288)
//   cbw     [4][256][256] ull    @ 1179648   (2097152)  [f][w][v]: bit l = sign cb[f][v][w*64+l]
//   cbT     [4][4][16384] ull    @ 3276800   (2097152)  [f][j][d]: bit l = sign cb[f][j*64+l][d]
//   simAB   [4][64][512] ushort  @ 5373952   (262144)   [..][0:256]=uh bf16, [256:512]=ul bf16
//   simF    (aliases simAB)      @ 5373952   [4][64][256] ushort raw q (used after last gemm)
//
// bit convention: bit = 1  <=>  value == -1;  product of bipolars = XOR of bits.

// ---- setup: pack input + init_estimates + codebook(word-major) in ONE dispatch ----
__global__ __launch_bounds__(1024) void pack_mega(
        const float* __restrict__ in, const float* __restrict__ est_f,
        const float* __restrict__ cb,
        ull* __restrict__ in_bits, ull* __restrict__ est_bits, ull* __restrict__ cbw) {
    int gw   = (int)((blockIdx.x * 1024 + threadIdx.x) >> 6);   // 344064 waves
    int lane = threadIdx.x & 63;
    if (gw < 16384) {
        float x = in[(size_t)gw * 64 + lane];
        ull m = __ballot(x < 0.0f);
        if (lane == 0) in_bits[gw] = m;
    } else if (gw < 81920) {
        int g = gw - 16384;
        float x = est_f[(size_t)g * 64 + lane];
        ull m = __ballot(x < 0.0f);
        if (lane == 0) est_bits[g] = m;
    } else {
        int g = gw - 81920;                       // (f*256+v)*256 + w
        int w = g & 255, fv = g >> 8;
        float x = cb[(size_t)fv * 16384 + (size_t)w * 64 + lane];
        ull m = __ballot(x < 0.0f);
        if (lane == 0) cbw[(size_t)((fv >> 8) * 256 + w) * 256 + (fv & 255)] = m;
    }
}

__global__ __launch_bounds__(1024) void pack_cbT(const ull* __restrict__ cbw, ull* __restrict__ cbT) {
    int gw   = (int)((blockIdx.x * 1024 + threadIdx.x) >> 6);
    int lane = threadIdx.x & 63;
    int f = gw >> 16, rem = gw & 65535, j = rem >> 14, d = rem & 16383;
    ull w = cbw[(size_t)(f * 256 + (d >> 6)) * 256 + j * 64 + lane];
    ull m = __ballot((w >> (d & 63)) & 1ull);
    if (lane == 0) cbT[(size_t)(f * 4 + j) * 16384 + d] = m;
}

__device__ __forceinline__ ushort_t f2bf(int x) {
    // exact for 0 <= x <= 256 (<= 8 significant bits)
    return (ushort_t)(__float_as_uint((float)x) >> 16);
}

// phase A v2: reuse-tiled popcount sim.
// grid 256 blocks x 1024. block = (f, vblk of 64 v, bblk of 4 b), XCD-swizzled so each
// XCD touches one f-slice only. Codebook slice (64v x 256w = 128KB) staged in LDS once,
// reused for 4 b. ne reads are wave-uniform broadcasts.
// mode 0: ne = in^e0^e1^e2^e3^ef, write uh/ul bf16 to simAB.  mode 1: ne = ef, write raw q to simF.
__global__ __launch_bounds__(1024) void simA2_kernel(
        const ull* __restrict__ in_bits, const ull* __restrict__ est_in,
        const ull* __restrict__ cbw, ushort_t* __restrict__ outq, int mode) {
    int bid = blockIdx.x;
    int f    = (bid & 7) >> 1;
    int sub  = (bid & 1) * 32 + (bid >> 3);       // 0..63
    int vblk = sub & 3, bblk = sub >> 2;          // 4 vblk x 16 bblk

    __shared__ ull s_cw[64][257];                 // 131.6KB
    __shared__ ull s_ne[4][257];                  // 8.2KB
    __shared__ short s_p[4][4][64];               // 2KB [bi][q][v]

    int t = threadIdx.x;

    // stage ne for this block's 4 b rows (1024 words, 1/thread)
    {
        int bl = t >> 8, w = t & 255;             // b-local 0..3, w 0..255
        int b = bblk * 4 + bl;
        ull e0 = est_in[(size_t)(b * 4 + 0) * 256 + w];
        ull e1 = est_in[(size_t)(b * 4 + 1) * 256 + w];
        ull e2 = est_in[(size_t)(b * 4 + 2) * 256 + w];
        ull e3 = est_in[(size_t)(b * 4 + 3) * 256 + w];
        ull ef = (f == 0) ? e0 : ((f == 1) ? e1 : ((f == 2) ? e2 : e3));
        ull val = mode ? ef
                       : (in_bits[(size_t)b * 256 + w] ^ e0 ^ e1 ^ e2 ^ e3 ^ ef);
        s_ne[bl][w] = val;
    }
    // stage codebook slice: 64 v x 256 w (16384 words, 16/thread, coalesced in v)
    #pragma unroll 4
    for (int i = 0; i < 16; ++i) {
        int idx = i * 1024 + t;
        int v = idx & 63, w = idx >> 6;
        s_cw[v][w] = cbw[(size_t)(f * 256 + w) * 256 + vblk * 64 + v];
    }
    __syncthreads();

    // popcount: wave = (bi, q); lane = v. cw read coalesced, ne read wave-uniform.
    {
        int lane = t & 63, wave = t >> 6;
        int bi = wave & 3, q = wave >> 2;
        int acc0 = 0, acc1 = 0;
        #pragma unroll 8
        for (int w = q * 64; w < q * 64 + 64; w += 2) {
            acc0 += __popcll(s_ne[bi][w]     ^ s_cw[lane][w]);
            acc1 += __popcll(s_ne[bi][w + 1] ^ s_cw[lane][w + 1]);
        }
        s_p[bi][q][lane] = (short)(acc0 + acc1);
    }
    __syncthreads();

    if (t < 256) {
        int bi = t >> 6, v2 = t & 63;
        int h = s_p[bi][0][v2] + s_p[bi][1][v2] + s_p[bi][2][v2] + s_p[bi][3][v2];
        int q16 = 16384 - h;                      // in [0,16384]
        int b = bblk * 4 + bi, v = vblk * 64 + v2;
        if (mode == 0) {
            size_t base = ((size_t)(f * 64 + b)) * 512 + v;
            outq[base]       = f2bf(q16 >> 8);    // uh in [0,64]
            outq[base + 256] = f2bf(q16 & 255);   // ul in [0,255]
        } else {
            outq[((size_t)(f * 64 + b)) * 256 + v] = (ushort_t)q16;
        }
    }
}

// phase B: one block per (f, dblk of 256 d) [XCD-swizzled], 512 threads (8 waves)
// est_bit(b,d) = ( 256*sum_v uh*cb + sum_v ul*cb < 8192*colsum )
__global__ __launch_bounds__(512) void gemm_kernel(
        const ull* __restrict__ cbT, const ushort_t* __restrict__ simAB,
        ull* __restrict__ est_out) {
    int bid = blockIdx.x;
    int fB   = (bid & 7) >> 1;
    int dblk = (bid & 1) * 32 + (bid >> 3);       // 0..63
    __shared__ int4 sB[8192];               // 128KB, frag order: (kc*16+nt)*64 + lane
    __shared__ ull s_ball[8][8][4];         // 2KB  [wave][nt&7][r]
    __shared__ int s_off[256];              // 1KB
    int t = threadIdx.x, lane = t & 63, wave = t >> 6;

    if (t < 256) {
        int d = dblk * 256 + t;
        int npop = 0;
        #pragma unroll
        for (int j = 0; j < 4; ++j) npop += __popcll(cbT[((size_t)fB * 4 + j) * 16384 + d]);
        s_off[t] = 8192 * (256 - 2 * npop);
    }

    #pragma unroll 4
    for (int it = 0; it < 16; ++it) {
        int flat = it * 512 + t;            // 8 kc * 16 nt * 64 lanes
        int kc = flat >> 10, nt = (flat >> 6) & 15, l = flat & 63;
        int v0 = kc * 32 + ((l >> 4) << 3);
        int d  = dblk * 256 + nt * 16 + (l & 15);
        ull w = cbT[((size_t)fB * 4 + (v0 >> 6)) * 16384 + d];
        unsigned bits = (unsigned)(w >> (v0 & 63)) & 0xFFu;
        int4 val;
        val.x = 0x3F803F80 | ((bits & 1u) << 15)        | ((bits & 2u) << 30);
        val.y = 0x3F803F80 | (((bits >> 2) & 1u) << 15) | (((bits >> 2) & 2u) << 30);
        val.z = 0x3F803F80 | (((bits >> 4) & 1u) << 15) | (((bits >> 4) & 2u) << 30);
        val.w = 0x3F803F80 | (((bits >> 6) & 1u) << 15) | (((bits >> 6) & 2u) << 30);
        sB[flat] = val;
    }

    int mw = wave & 3, ntb = (wave >> 2) << 3;
    const ushort_t* abase = simAB
        + ((size_t)(fB * 64 + mw * 16 + (lane & 15))) * 512 + ((lane >> 4) << 3);
    bf16x8 Ahi[8], Alo[8];
    #pragma unroll
    for (int kc = 0; kc < 8; ++kc) {
        Ahi[kc] = *(const bf16x8*)(abase + kc * 32);
        Alo[kc] = *(const bf16x8*)(abase + 256 + kc * 32);
    }
    __syncthreads();

    #pragma unroll 2
    for (int ntl = 0; ntl < 8; ++ntl) {
        int nt = ntb + ntl;
        f32x4 acch = {0.f, 0.f, 0.f, 0.f}, accl = {0.f, 0.f, 0.f, 0.f};
        #pragma unroll
        for (int kc = 0; kc < 8; ++kc) {
            bf16x8 B = *(const bf16x8*)&sB[(kc * 16 + nt) * 64 + lane];
            acch = __builtin_amdgcn_mfma_f32_16x16x32_bf16(Ahi[kc], B, acch, 0, 0, 0);
            accl = __builtin_amdgcn_mfma_f32_16x16x32_bf16(Alo[kc], B, accl, 0, 0, 0);
        }
        float offf = (float)s_off[nt * 16 + (lane & 15)];
        #pragma unroll
        for (int r = 0; r < 4; ++r) {
            float S = 256.0f * acch[r] + accl[r];   // exact int < 2^23
            // C-frag: row m = mw*16 + (lane>>4)*4 + r, col d-local = lane&15
            ull m = __ballot(S < offf);
            if (lane == 0) s_ball[wave][nt & 7][r] = m;
        }
    }
    __syncthreads();

    if (t < 256) {
        int b = t >> 2, w4 = t & 3;                 // est word (b, d-word dblk*4+w4)
        int wv = (b >> 4) + ((w4 >= 2) ? 4 : 0);    // writer wave for (mw=b>>4, nt-half)
        ull word = 0;
        #pragma unroll
        for (int k = 0; k < 4; ++k) {
            int nt = w4 * 4 + k;
            ull m = s_ball[wv][nt & 7][b & 3];
            word |= ((m >> (((b >> 2) & 3) * 16)) & 0xFFFFull) << (k * 16);
        }
        est_out[((size_t)(b * 4 + fB)) * 256 + dblk * 4 + w4] = word;
    }
}

// final: argmax|2q-16384| per (b,f) from simF (blocks 0..255) + unpack est -> +-1.0f (all blocks)
__global__ __launch_bounds__(256) void final2_kernel(
        const ull* __restrict__ est, const ushort_t* __restrict__ simF,
        float* __restrict__ out) {
    int t = threadIdx.x;
    if (blockIdx.x < 256 && t < 64) {
        int b = blockIdx.x >> 2, f = blockIdx.x & 3;
        const ushort_t* sf = simF + ((size_t)(f * 64 + b)) * 256 + t * 4;
        int best_a = -1, best_v = 0;
        #pragma unroll
        for (int k = 0; k < 4; ++k) {
            int sim = 2 * (int)sf[k] - 16384;
            int a = sim < 0 ? -sim : sim;
            if (a > best_a) { best_a = a; best_v = t * 4 + k; }  // strict > keeps first index
        }
        #pragma unroll
        for (int off = 1; off < 64; off <<= 1) {
            int oa = __shfl_xor(best_a, off);
            int ov = __shfl_xor(best_v, off);
            if (oa > best_a || (oa == best_a && ov < best_v)) { best_a = oa; best_v = ov; }
        }
        if (t == 0) out[4194304 + b * 4 + f] = (float)best_v;
    }
    // unpack: 4194304 floats over 2048 blocks -> 2048 floats/block, 8/thread
    int flat = blockIdx.x * 2048 + t * 8;
    ull w = est[flat >> 6];
    unsigned bits = (unsigned)(w >> (flat & 63)) & 0xFFu;
    float4 lo, hi;
    lo.x = (bits & 1u)   ? -1.0f : 1.0f;
    lo.y = (bits & 2u)   ? -1.0f : 1.0f;
    lo.z = (bits & 4u)   ? -1.0f : 1.0f;
    lo.w = (bits & 8u)   ? -1.0f : 1.0f;
    hi.x = (bits & 16u)  ? -1.0f : 1.0f;
    hi.y = (bits & 32u)  ? -1.0f : 1.0f;
    hi.z = (bits & 64u)  ? -1.0f : 1.0f;
    hi.w = (bits & 128u) ? -1.0f : 1.0f;
    *(float4*)(out + flat)     = lo;
    *(float4*)(out + flat + 4) = hi;
}

extern "C" void kernel_launch(void* const* d_in, const int* in_sizes, int n_in,
                              void* d_out, int out_size, void* d_ws, size_t ws_size,
                              hipStream_t stream) {
    const float* input    = (const float*)d_in[0];
    const float* init_est = (const float*)d_in[1];
    const float* cb       = (const float*)d_in[2];
    float* out = (float*)d_out;
    char* ws = (char*)d_ws;

    ull* in_bits    = (ull*)(ws + 0);
    ull* est0       = (ull*)(ws + 131072);
    ull* est1       = (ull*)(ws + 655360);
    ull* cbw        = (ull*)(ws + 1179648);
    ull* cbT        = (ull*)(ws + 3276800);
    ushort_t* simAB = (ushort_t*)(ws + 5373952);
    ushort_t* simF  = simAB;   // reused after last gemm

    // setup: 2 dispatches
    pack_mega<<<21504, 1024, 0, stream>>>(input, init_est, cb, in_bits, est0, cbw);
    pack_cbT<<<16384, 1024, 0, stream>>>(cbw, cbT);

    ull* bufs[2] = { est0, est1 };
    for (int i = 0; i < 10; ++i) {
        simA2_kernel<<<256, 1024, 0, stream>>>(in_bits, bufs[i & 1], cbw, simAB, 0);
        gemm_kernel<<<256, 512, 0, stream>>>(cbT, simAB, bufs[(i & 1) ^ 1]);
    }
    // final est in est0: raw sim(est,cb) then argmax+unpack
    simA2_kernel<<<256, 1024, 0, stream>>>(in_bits, est0, cbw, simF, 1);
    final2_kernel<<<2048, 256, 0, stream>>>(est0, simF, out);
}

// Round 7
// 318.926 us; speedup vs baseline: 5.5579x; 1.1395x over previous
//
#include <hip/hip_runtime.h>
#include <stdint.h>

typedef unsigned long long ull;
typedef unsigned short ushort_t;
typedef __attribute__((ext_vector_type(8))) short bf16x8;
typedef __attribute__((ext_vector_type(4))) float f32x4;

// sizes: b=64, f=4, v=256, d=16384, ITERS=10; d-words = 256, v-words = 4
//
// ws layout (bytes):
//   in_bits [64][256] ull        @ 0         (131072)
//   est0    [64][4][256] ull     @ 131072    (524288)
//   est1    [64][4][256] ull     @ 655360    (524288)
//   cbw     [4][256][256] ull    @ 1179648   (2097152)  [f][w][v]: bit l = sign cb[f][v][w*64+l]
//   cbT     [4][4][16384] ull    @ 3276800   (2097152)  [f][j][d]: bit l = sign cb[f][j*64+l][d]
//   simAB   [4][64][512] ushort  @ 5373952   (262144)   [0:256]=sh bf16 (signed), [256:512]=sl bf16
//   simF    (aliases simAB)      @ 5373952   [4][64][256] ushort raw q16
//
// bit convention: bit = 1  <=>  value == -1;  product of bipolars = XOR of bits.
// signed split: sim = 2*q16 - 16384 = 256*sh + sl, sh = sim>>8 in [-64,64], sl = sim&255.
// est bit = ( sum_v sim[v]*cb[v,d] < 0 )  -- no colsum offset needed.

// ---- setup: pack input + init_estimates + codebook in ONE dispatch, 16 words/wave ----
__global__ __launch_bounds__(1024) void pack_mega(
        const float* __restrict__ in, const float* __restrict__ est_f,
        const float* __restrict__ cb,
        ull* __restrict__ in_bits, ull* __restrict__ est_bits, ull* __restrict__ cbw) {
    int wid  = (int)((blockIdx.x * 1024 + threadIdx.x) >> 6);   // 21504 waves
    int lane = threadIdx.x & 63;
    int w0 = wid * 16;                        // first word of this wave's group
    const float* s;
    int wloc;
    if (w0 < 16384)      { s = in;    wloc = w0; }
    else if (w0 < 81920) { s = est_f; wloc = w0 - 16384; }
    else                 { s = cb;    wloc = w0 - 81920; }
    ull ball[16];
    #pragma unroll
    for (int k = 0; k < 16; ++k) {
        float x = s[(size_t)(wloc + k) * 64 + lane];
        ball[k] = __ballot(x < 0.0f);
    }
    if (lane == 0) {
        if (w0 < 16384) {
            #pragma unroll
            for (int k = 0; k < 16; ++k) in_bits[wloc + k] = ball[k];
        } else if (w0 < 81920) {
            #pragma unroll
            for (int k = 0; k < 16; ++k) est_bits[wloc + k] = ball[k];
        } else {
            #pragma unroll
            for (int k = 0; k < 16; ++k) {
                int g = wloc + k;             // (f*256+v)*256 + w
                int f = g >> 16, v = (g >> 8) & 255, w = g & 255;
                cbw[(size_t)(f * 256 + w) * 256 + v] = ball[k];
            }
        }
    }
}

// 16 d per wave: 1 load + 16 ballots + 16 stores
__global__ __launch_bounds__(1024) void pack_cbT(const ull* __restrict__ cbw, ull* __restrict__ cbT) {
    int wid  = (int)((blockIdx.x * 1024 + threadIdx.x) >> 6);   // 16384 waves
    int lane = threadIdx.x & 63;
    int f = wid >> 12, j = (wid >> 10) & 3, w = (wid >> 2) & 255, s2 = wid & 3;
    ull cw = cbw[(size_t)(f * 256 + w) * 256 + j * 64 + lane];
    ull ball[16];
    #pragma unroll
    for (int k = 0; k < 16; ++k)
        ball[k] = __ballot((cw >> (s2 * 16 + k)) & 1ull);
    if (lane == 0) {
        #pragma unroll
        for (int k = 0; k < 16; ++k)
            cbT[(size_t)(f * 4 + j) * 16384 + w * 64 + s2 * 16 + k] = ball[k];
    }
}

// phase A v3: reuse-tiled popcount sim, conflict-free LDS ([w][v] layout).
// grid 256 x 1024; block = XCD-swizzled (f, vblk of 64 v, bblk of 4 b).
// mode 0: write signed-split sh/sl bf16 to simAB.  mode 1: ne = est_f, write raw q16 to simF.
__global__ __launch_bounds__(1024) void simA3_kernel(
        const ull* __restrict__ in_bits, const ull* __restrict__ est_in,
        const ull* __restrict__ cbw, ushort_t* __restrict__ outq, int mode) {
    int bid = blockIdx.x;
    int f    = (bid & 7) >> 1;
    int sub  = (bid & 1) * 32 + (bid >> 3);       // 0..63
    int vblk = sub & 3, bblk = sub >> 2;          // 4 vblk x 16 bblk

    __shared__ ull s_cw[256][64];                 // 128KB, [w][v-local]: reads contiguous
    __shared__ ull s_ne[4][256];                  // 8KB
    __shared__ short s_p[4][4][64];               // 2KB [bi][q][v]

    int t = threadIdx.x;

    // stage ne for this block's 4 b rows (1024 words, 1/thread)
    {
        int bl = t >> 8, w = t & 255;
        int b = bblk * 4 + bl;
        ull e0 = est_in[(size_t)(b * 4 + 0) * 256 + w];
        ull e1 = est_in[(size_t)(b * 4 + 1) * 256 + w];
        ull e2 = est_in[(size_t)(b * 4 + 2) * 256 + w];
        ull e3 = est_in[(size_t)(b * 4 + 3) * 256 + w];
        ull ef = (f == 0) ? e0 : ((f == 1) ? e1 : ((f == 2) ? e2 : e3));
        s_ne[bl][w] = mode ? ef
                           : (in_bits[(size_t)b * 256 + w] ^ e0 ^ e1 ^ e2 ^ e3 ^ ef);
    }
    // stage codebook slice 256w x 64v (16384 words, 16/thread, coalesced both sides)
    #pragma unroll 4
    for (int i = 0; i < 16; ++i) {
        int idx = i * 1024 + t;
        int w = idx >> 6, v = idx & 63;
        s_cw[w][v] = cbw[(size_t)(f * 256 + w) * 256 + vblk * 64 + v];
    }
    __syncthreads();

    // popcount: wave = (bi,q); lane = v-local. cw read contiguous 512B, ne broadcast.
    {
        int lane = t & 63, wave = t >> 6;
        int bi = wave & 3, q = wave >> 2;
        int acc = 0;
        #pragma unroll 8
        for (int w = q * 64; w < q * 64 + 64; ++w)
            acc += __popcll(s_ne[bi][w] ^ s_cw[w][lane]);
        s_p[bi][q][lane] = (short)acc;
    }
    __syncthreads();

    if (t < 256) {
        int bi = t >> 6, v2 = t & 63;
        int h = s_p[bi][0][v2] + s_p[bi][1][v2] + s_p[bi][2][v2] + s_p[bi][3][v2];
        int b = bblk * 4 + bi, v = vblk * 64 + v2;
        if (mode == 0) {
            int sim = 16384 - 2 * h;                  // in [-16384, 16384]
            int sh = sim >> 8, sl = sim & 255;        // sim = 256*sh + sl exactly
            size_t base = ((size_t)(f * 64 + b)) * 512 + v;
            outq[base]       = (ushort_t)(__float_as_uint((float)sh) >> 16);  // bf16 exact
            outq[base + 256] = (ushort_t)(__float_as_uint((float)sl) >> 16);  // bf16 exact
        } else {
            outq[((size_t)(f * 64 + b)) * 256 + v] = (ushort_t)(16384 - h);   // raw q16
        }
    }
}

// phase B v3: one block per (f, dblk of 256 d) [XCD-swizzled], 512 threads (8 waves)
// est_bit(b,d) = ( 256*sum_v sh*cb + sum_v sl*cb < 0 )
__global__ __launch_bounds__(512) void gemm_kernel(
        const ull* __restrict__ cbT, const ushort_t* __restrict__ simAB,
        ull* __restrict__ est_out) {
    int bid = blockIdx.x;
    int fB   = (bid & 7) >> 1;
    int dblk = (bid & 1) * 32 + (bid >> 3);       // 0..63
    __shared__ int4 sB[8192];               // 128KB, frag order: (kc*16+nt)*64 + lane
    __shared__ ull s_ball[8][8][4];         // 2KB  [wave][nt&7][r]
    int t = threadIdx.x, lane = t & 63, wave = t >> 6;

    // unpack codebook bits -> bf16 MFMA B-frags in LDS
    #pragma unroll 4
    for (int it = 0; it < 16; ++it) {
        int flat = it * 512 + t;            // 8 kc * 16 nt * 64 lanes
        int kc = flat >> 10, nt = (flat >> 6) & 15, l = flat & 63;
        int v0 = kc * 32 + ((l >> 4) << 3);
        int d  = dblk * 256 + nt * 16 + (l & 15);
        ull w = cbT[((size_t)fB * 4 + (v0 >> 6)) * 16384 + d];
        unsigned bits = (unsigned)(w >> (v0 & 63)) & 0xFFu;
        int4 val;
        val.x = 0x3F803F80 | ((bits & 1u) << 15)        | ((bits & 2u) << 30);
        val.y = 0x3F803F80 | (((bits >> 2) & 1u) << 15) | (((bits >> 2) & 2u) << 30);
        val.z = 0x3F803F80 | (((bits >> 4) & 1u) << 15) | (((bits >> 4) & 2u) << 30);
        val.w = 0x3F803F80 | (((bits >> 6) & 1u) << 15) | (((bits >> 6) & 2u) << 30);
        sB[flat] = val;
    }

    // A-frags from global simAB (L2-resident)
    int mw = wave & 3, ntb = (wave >> 2) << 3;
    const ushort_t* abase = simAB
        + ((size_t)(fB * 64 + mw * 16 + (lane & 15))) * 512 + ((lane >> 4) << 3);
    bf16x8 Ahi[8], Alo[8];
    #pragma unroll
    for (int kc = 0; kc < 8; ++kc) {
        Ahi[kc] = *(const bf16x8*)(abase + kc * 32);
        Alo[kc] = *(const bf16x8*)(abase + 256 + kc * 32);
    }
    __syncthreads();

    #pragma unroll 2
    for (int ntl = 0; ntl < 8; ++ntl) {
        int nt = ntb + ntl;
        f32x4 acch = {0.f, 0.f, 0.f, 0.f}, accl = {0.f, 0.f, 0.f, 0.f};
        #pragma unroll
        for (int kc = 0; kc < 8; ++kc) {
            bf16x8 B = *(const bf16x8*)&sB[(kc * 16 + nt) * 64 + lane];
            acch = __builtin_amdgcn_mfma_f32_16x16x32_bf16(Ahi[kc], B, acch, 0, 0, 0);
            accl = __builtin_amdgcn_mfma_f32_16x16x32_bf16(Alo[kc], B, accl, 0, 0, 0);
        }
        #pragma unroll
        for (int r = 0; r < 4; ++r) {
            float S = 256.0f * acch[r] + accl[r];   // exact int, |S| < 2^23
            // C-frag row m = mw*16 + (lane>>4)*4 + r, col d-local = lane&15
            ull m = __ballot(S < 0.0f);
            if (lane == 0) s_ball[wave][nt & 7][r] = m;
        }
    }
    __syncthreads();

    if (t < 256) {
        int b = t >> 2, w4 = t & 3;                 // est word (b, d-word dblk*4+w4)
        int wv = (b >> 4) + ((w4 >= 2) ? 4 : 0);    // writer wave for (mw=b>>4, nt-half)
        ull word = 0;
        #pragma unroll
        for (int k = 0; k < 4; ++k) {
            int nt = w4 * 4 + k;
            ull m = s_ball[wv][nt & 7][b & 3];
            word |= ((m >> (((b >> 2) & 3) * 16)) & 0xFFFFull) << (k * 16);
        }
        est_out[((size_t)(b * 4 + fB)) * 256 + dblk * 4 + w4] = word;
    }
}

// final: argmax|2q-16384| per (b,f) from simF (blocks 0..255) + unpack est -> +-1.0f
__global__ __launch_bounds__(256) void final2_kernel(
        const ull* __restrict__ est, const ushort_t* __restrict__ simF,
        float* __restrict__ out) {
    int t = threadIdx.x;
    if (blockIdx.x < 256 && t < 64) {
        int b = blockIdx.x >> 2, f = blockIdx.x & 3;
        const ushort_t* sf = simF + ((size_t)(f * 64 + b)) * 256 + t * 4;
        int best_a = -1, best_v = 0;
        #pragma unroll
        for (int k = 0; k < 4; ++k) {
            int sim = 2 * (int)sf[k] - 16384;
            int a = sim < 0 ? -sim : sim;
            if (a > best_a) { best_a = a; best_v = t * 4 + k; }  // strict > keeps first index
        }
        #pragma unroll
        for (int off = 1; off < 64; off <<= 1) {
            int oa = __shfl_xor(best_a, off);
            int ov = __shfl_xor(best_v, off);
            if (oa > best_a || (oa == best_a && ov < best_v)) { best_a = oa; best_v = ov; }
        }
        if (t == 0) out[4194304 + b * 4 + f] = (float)best_v;
    }
    // unpack: 4194304 floats over 2048 blocks -> 2048 floats/block, 8/thread
    int flat = blockIdx.x * 2048 + t * 8;
    ull w = est[flat >> 6];
    unsigned bits = (unsigned)(w >> (flat & 63)) & 0xFFu;
    float4 lo, hi;
    lo.x = (bits & 1u)   ? -1.0f : 1.0f;
    lo.y = (bits & 2u)   ? -1.0f : 1.0f;
    lo.z = (bits & 4u)   ? -1.0f : 1.0f;
    lo.w = (bits & 8u)   ? -1.0f : 1.0f;
    hi.x = (bits & 16u)  ? -1.0f : 1.0f;
    hi.y = (bits & 32u)  ? -1.0f : 1.0f;
    hi.z = (bits & 64u)  ? -1.0f : 1.0f;
    hi.w = (bits & 128u) ? -1.0f : 1.0f;
    *(float4*)(out + flat)     = lo;
    *(float4*)(out + flat + 4) = hi;
}

extern "C" void kernel_launch(void* const* d_in, const int* in_sizes, int n_in,
                              void* d_out, int out_size, void* d_ws, size_t ws_size,
                              hipStream_t stream) {
    const float* input    = (const float*)d_in[0];
    const float* init_est = (const float*)d_in[1];
    const float* cb       = (const float*)d_in[2];
    float* out = (float*)d_out;
    char* ws = (char*)d_ws;

    ull* in_bits    = (ull*)(ws + 0);
    ull* est0       = (ull*)(ws + 131072);
    ull* est1       = (ull*)(ws + 655360);
    ull* cbw        = (ull*)(ws + 1179648);
    ull* cbT        = (ull*)(ws + 3276800);
    ushort_t* simAB = (ushort_t*)(ws + 5373952);
    ushort_t* simF  = simAB;   // reused after last gemm

    // setup: 2 dispatches (16 words per wave each)
    pack_mega<<<1344, 1024, 0, stream>>>(input, init_est, cb, in_bits, est0, cbw);
    pack_cbT<<<1024, 1024, 0, stream>>>(cbw, cbT);

    ull* bufs[2] = { est0, est1 };
    for (int i = 0; i < 10; ++i) {
        simA3_kernel<<<256, 1024, 0, stream>>>(in_bits, bufs[i & 1], cbw, simAB, 0);
        gemm_kernel<<<256, 512, 0, stream>>>(cbT, simAB, bufs[(i & 1) ^ 1]);
    }
    // final est in est0: raw sim(est,cb) then argmax+unpack
    simA3_kernel<<<256, 1024, 0, stream>>>(in_bits, est0, cbw, simF, 1);
    final2_kernel<<<2048, 256, 0, stream>>>(est0, simF, out);
}